// Round 3
// baseline (721.515 us; speedup 1.0000x reference)
//
#include <hip/hip_runtime.h>
#include <hip/hip_bf16.h>
#include <math.h>

#define NB 1024
#define NC 100000
#define ND 512
#define SSCALE 64.0f
#define MMARGIN 0.5f

#define BM 256                       // rows per chunk
#define BN 64                        // classes per block (panel width)
#define BK 64                        // K per A-stage step
#define NCHUNK (NB / BM)             // 4 row chunks
#define NKS (ND / BK)                // 8 K-steps
#define NITER (NCHUNK * NKS)         // 32
#define NCT ((NC + BN - 1) / BN)     // 1563 blocks

#define ABASE 0                      // A: 2 x 32KB double buffer
#define ABUF  32768
#define BBASE 65536                  // B: 64 x 512 bf16 = 64KB, full K

typedef __bf16 bf16x8 __attribute__((ext_vector_type(8)));
typedef float f32x4 __attribute__((ext_vector_type(4)));

__device__ __forceinline__ void gload_lds16(const void* g, void* l) {
    __builtin_amdgcn_global_load_lds(
        (const __attribute__((address_space(1))) unsigned int*)g,
        (__attribute__((address_space(3))) unsigned int*)l, 16, 0, 0);
}

// ---------------------------------------------------------------------------
// ws layout: [0,1MB) xnb bf16[NB][ND] ; then sums float[NB] ; tgt float[NB]
// ---------------------------------------------------------------------------

__global__ void prep_kernel(const float* __restrict__ x, __bf16* __restrict__ xnb) {
    const int row = blockIdx.x;
    const int tid = threadIdx.x;
    const float2 v = *reinterpret_cast<const float2*>(x + (size_t)row * ND + tid * 2);
    float ss = v.x * v.x + v.y * v.y;
#pragma unroll
    for (int m = 1; m < 64; m <<= 1) ss += __shfl_xor(ss, m);
    __shared__ float wsum[4];
    if ((tid & 63) == 0) wsum[tid >> 6] = ss;
    __syncthreads();
    const float tot = wsum[0] + wsum[1] + wsum[2] + wsum[3];
    const float inv = 1.0f / fmaxf(sqrtf(tot), 1e-12f);
    __bf16* dst = xnb + (size_t)row * ND + tid * 2;
    dst[0] = (__bf16)(v.x * inv);
    dst[1] = (__bf16)(v.y * inv);
}

__global__ void target_kernel(const __bf16* __restrict__ xnb, const float* __restrict__ Wg,
                              const int* __restrict__ labels, float* __restrict__ tgt) {
    const int wid  = threadIdx.x >> 6;
    const int lane = threadIdx.x & 63;
    const int row  = blockIdx.x * 4 + wid;
    const int lab  = labels[row];
    const int k    = lane * 8;
    const bf16x8 xv = *reinterpret_cast<const bf16x8*>(xnb + (size_t)row * ND + k);
    const float* wr = Wg + (size_t)lab * ND + k;
    const float4 w0 = *reinterpret_cast<const float4*>(wr);
    const float4 w1 = *reinterpret_cast<const float4*>(wr + 4);
    float s = (float)xv[0] * w0.x + (float)xv[1] * w0.y + (float)xv[2] * w0.z + (float)xv[3] * w0.w
            + (float)xv[4] * w1.x + (float)xv[5] * w1.y + (float)xv[6] * w1.z + (float)xv[7] * w1.w;
#pragma unroll
    for (int m = 1; m < 64; m <<= 1) s += __shfl_xor(s, m);
    if (lane == 0) tgt[row] = s;
}

// Persistent-panel GEMM: block owns 64 classes, stages full-K B once (fp32->bf16,
// 64KB swizzled), sweeps all 1024 rows in 4 chunks of 256 with A double-buffered
// via global_load_lds (pre-swizzled source). Fused exp + row-sum epilogue/chunk.
// 512 thr / 8 waves (4r x 2c, wave tile 64x32). LDS 128KB -> 1 block/CU.
__global__ __launch_bounds__(512, 2) void gemm_exp_kernel(const __bf16* __restrict__ xnb,
                                                          const float* __restrict__ Wg,
                                                          float* __restrict__ sums) {
    __shared__ char lds[131072];
    const int tid  = threadIdx.x;
    const int wid  = tid >> 6;
    const int lane = tid & 63;
    const int l15  = lane & 15;
    const int lhi  = lane >> 4;
    const int wr   = wid >> 1;       // 0..3 : row group (64 rows)
    const int wc   = wid & 1;        // 0..1 : col group (32 cols)
    const int c0   = blockIdx.x * BN;

    // ---- stage B panel once: 64 cls x 512 K, fp32 -> bf16, swizzled ----
    // thread: cls = tid>>3 (0..63), bqp = tid&7 -> 16 consecutive float4 (256B)
    {
        const int cls = tid >> 3;
        const int bqp = tid & 7;
        const bool ok = (c0 + cls) < NC;
        const float* srow = Wg + (size_t)(c0 + cls) * ND + bqp * 64;
#pragma unroll
        for (int p = 0; p < 8; ++p) {     // p: bf16 16B-chunk within thread's span
            float4 v0 = make_float4(0.f, 0.f, 0.f, 0.f), v1 = v0;
            if (ok) {
                v0 = *reinterpret_cast<const float4*>(srow + p * 8);
                v1 = *reinterpret_cast<const float4*>(srow + p * 8 + 4);
            }
            struct alignas(16) bf8s { __bf16 h[8]; };
            bf8s h;
            h.h[0] = (__bf16)v0.x; h.h[1] = (__bf16)v0.y; h.h[2] = (__bf16)v0.z; h.h[3] = (__bf16)v0.w;
            h.h[4] = (__bf16)v1.x; h.h[5] = (__bf16)v1.y; h.h[6] = (__bf16)v1.z; h.h[7] = (__bf16)v1.w;
            const int ck = bqp * 8 + p;   // 16B-chunk index within the 1024B row
            *reinterpret_cast<bf8s*>(lds + BBASE + cls * 1024 + ((ck ^ (cls & 7)) << 4)) = h;
        }
    }

    // ---- A stage: async, linear dest; source pre-swizzled (rule 21) ----
    auto stageA = [&](int it, int buf) {
        const int ch = it >> 3, t = it & 7;
#pragma unroll
        for (int s = 0; s < 4; ++s) {
            const int lin = s * 8192 + wid * 1024 + (lane << 4);
            const int row = lin >> 7;               // /128B per row
            const int cnk = (lin >> 4) & 7;
            const int sc  = cnk ^ (row & 7);
            const char* src = (const char*)xnb + (size_t)(ch * BM + row) * 1024 + t * 128 + sc * 16;
            gload_lds16(src, lds + ABASE + buf * ABUF + s * 8192 + wid * 1024);
        }
    };

    auto compute = [&](int buf, int t, f32x4 (&acc)[4][2]) {
#pragma unroll
        for (int kk = 0; kk < 2; ++kk) {
            bf16x8 a[4], b[2];
#pragma unroll
            for (int i = 0; i < 4; ++i) {
                const int r = wr * 64 + i * 16 + l15;
                const int ck = (kk << 2) | lhi;
                a[i] = *reinterpret_cast<const bf16x8*>(
                    lds + ABASE + buf * ABUF + r * 128 + ((ck ^ (r & 7)) << 4));
            }
#pragma unroll
            for (int j = 0; j < 2; ++j) {
                const int cls = wc * 32 + j * 16 + l15;
                const int ck  = t * 8 + kk * 4 + lhi;     // chunk within full-K row
                b[j] = *reinterpret_cast<const bf16x8*>(
                    lds + BBASE + cls * 1024 + ((ck ^ (cls & 7)) << 4));
            }
#pragma unroll
            for (int i = 0; i < 4; ++i)
#pragma unroll
                for (int j = 0; j < 2; ++j)
                    acc[i][j] = __builtin_amdgcn_mfma_f32_16x16x32_bf16(a[i], b[j], acc[i][j], 0, 0, 0);
        }
    };

    stageA(0, 0);
    __syncthreads();   // drains B ds_writes + A(0) gload_lds

    int buf = 0;
#pragma unroll 1
    for (int ch = 0; ch < NCHUNK; ++ch) {
        f32x4 acc[4][2] = {};
#pragma unroll 1
        for (int t = 0; t < NKS; ++t) {
            const int it = ch * NKS + t;
            if (it + 1 < NITER) stageA(it + 1, buf ^ 1);
            compute(buf, t, acc);
            __syncthreads();   // readers done with buf; next stage landed (vmcnt)
            buf ^= 1;
        }
        // ---- epilogue for this chunk: exp + row-sum + atomic ----
#pragma unroll
        for (int i = 0; i < 4; ++i) {
#pragma unroll
            for (int r = 0; r < 4; ++r) {
                float v = 0.f;
#pragma unroll
                for (int j = 0; j < 2; ++j) {
                    const int c = c0 + wc * 32 + j * 16 + l15;
                    v += (c < NC) ? __expf(SSCALE * acc[i][j][r]) : 0.f;
                }
                v += __shfl_xor(v, 1);
                v += __shfl_xor(v, 2);
                v += __shfl_xor(v, 4);
                v += __shfl_xor(v, 8);
                if (l15 == 0) {
                    const int row = ch * BM + wr * 64 + i * 16 + lhi * 4 + r;
                    atomicAdd(&sums[row], v);
                }
            }
        }
    }
}

__global__ void finalize_kernel(const float* __restrict__ sums, const float* __restrict__ tgt,
                                float* __restrict__ out) {
    const int tid  = threadIdx.x;
    const int wid  = tid >> 6;
    const int lane = tid & 63;
    float t  = tgt[tid];
    const float se = sums[tid];
    t = fminf(fmaxf(t, -1.0f + 1e-7f), 1.0f - 1e-7f);
    const float numer = SSCALE * cosf(acosf(t) + MMARGIN);
    const float excl  = se - expf(SSCALE * t);
    float L = numer - logf(expf(numer) + excl);
#pragma unroll
    for (int m = 1; m < 64; m <<= 1) L += __shfl_xor(L, m);
    __shared__ float ws2[16];
    if (lane == 0) ws2[wid] = L;
    __syncthreads();
    if (tid == 0) {
        float tot = 0.f;
        for (int i = 0; i < 16; ++i) tot += ws2[i];
        out[0] = -(tot / (float)NB);
    }
}

extern "C" void kernel_launch(void* const* d_in, const int* in_sizes, int n_in,
                              void* d_out, int out_size, void* d_ws, size_t ws_size,
                              hipStream_t stream) {
    const float* x      = (const float*)d_in[0];
    const int*   labels = (const int*)d_in[1];
    const float* W      = (const float*)d_in[2];
    float* out = (float*)d_out;

    char* wsb = (char*)d_ws;
    __bf16* xnb  = (__bf16*)wsb;
    float*  sums = (float*)(wsb + (size_t)NB * ND * 2);
    float*  tgt  = sums + NB;

    hipMemsetAsync(sums, 0, NB * sizeof(float), stream);
    prep_kernel<<<NB, 256, 0, stream>>>(x, xnb);
    target_kernel<<<NB / 4, 256, 0, stream>>>(xnb, W, labels, tgt);
    gemm_exp_kernel<<<NCT, 512, 0, stream>>>(xnb, W, sums);
    finalize_kernel<<<1, 1024, 0, stream>>>(sums, tgt, out);
}

// Round 4
// 238.070 us; speedup vs baseline: 3.0307x; 3.0307x over previous
//
#include <hip/hip_runtime.h>
#include <hip/hip_bf16.h>
#include <math.h>

#define NB 1024
#define NC 100000
#define ND 512
#define SSCALE 64.0f
#define MMARGIN 0.5f

#define BM 256                       // rows per block (no row sweep: grid covers rows)
#define BN 128                       // classes per block
#define BK 32                        // K per step
#define NKS (ND / BK)                // 16 K-steps
#define NRT (NB / BM)                // 4 row tiles
#define NCT ((NC + BN - 1) / BN)     // 782 col tiles
#define GRIDSZ (NRT * NCT)           // 3128 = 8 * 391 exact -> bijective XCD swizzle

#define ABASE 0                      // A: 2 x 16KB (256 rows x 64B)
#define ABUF  16384
#define BBASE 32768                  // B: 2 x 8KB (128 cls x 64B)
#define BBUF  8192

typedef __bf16 bf16x8 __attribute__((ext_vector_type(8)));
typedef float f32x4 __attribute__((ext_vector_type(4)));

__device__ __forceinline__ void gload_lds16(const void* g, void* l) {
    __builtin_amdgcn_global_load_lds(
        (const __attribute__((address_space(1))) unsigned int*)g,
        (__attribute__((address_space(3))) unsigned int*)l, 16, 0, 0);
}

// ---------------------------------------------------------------------------
// ws layout: [0,1MB) xnb bf16[NB][ND] ; then sums float[NB] ; tgt float[NB]
// ---------------------------------------------------------------------------

__global__ void prep_kernel(const float* __restrict__ x, __bf16* __restrict__ xnb) {
    const int row = blockIdx.x;
    const int tid = threadIdx.x;
    const float2 v = *reinterpret_cast<const float2*>(x + (size_t)row * ND + tid * 2);
    float ss = v.x * v.x + v.y * v.y;
#pragma unroll
    for (int m = 1; m < 64; m <<= 1) ss += __shfl_xor(ss, m);
    __shared__ float wsum[4];
    if ((tid & 63) == 0) wsum[tid >> 6] = ss;
    __syncthreads();
    const float tot = wsum[0] + wsum[1] + wsum[2] + wsum[3];
    const float inv = 1.0f / fmaxf(sqrtf(tot), 1e-12f);
    __bf16* dst = xnb + (size_t)row * ND + tid * 2;
    dst[0] = (__bf16)(v.x * inv);
    dst[1] = (__bf16)(v.y * inv);
}

__global__ void target_kernel(const __bf16* __restrict__ xnb, const float* __restrict__ Wg,
                              const int* __restrict__ labels, float* __restrict__ tgt) {
    const int wid  = threadIdx.x >> 6;
    const int lane = threadIdx.x & 63;
    const int row  = blockIdx.x * 4 + wid;
    const int lab  = labels[row];
    const int k    = lane * 8;
    const bf16x8 xv = *reinterpret_cast<const bf16x8*>(xnb + (size_t)row * ND + k);
    const float* wr = Wg + (size_t)lab * ND + k;
    const float4 w0 = *reinterpret_cast<const float4*>(wr);
    const float4 w1 = *reinterpret_cast<const float4*>(wr + 4);
    float s = (float)xv[0] * w0.x + (float)xv[1] * w0.y + (float)xv[2] * w0.z + (float)xv[3] * w0.w
            + (float)xv[4] * w1.x + (float)xv[5] * w1.y + (float)xv[6] * w1.z + (float)xv[7] * w1.w;
#pragma unroll
    for (int m = 1; m < 64; m <<= 1) s += __shfl_xor(s, m);
    if (lane == 0) tgt[row] = s;
}

// 256x128xK GEMM, BK=32, both operands LDS-double-buffered, ONE barrier/K-step.
// A (bf16 xnb) via global_load_lds w16, pre-swizzled source (rule 21).
// B (fp32 W) reg-staged: loads issued early, cvt+swizzled ds_write after compute
// (overlaps), lands before the step barrier. 48KB LDS -> 2 blocks/CU, 16 waves.
// Fused exp + row-sum + atomic epilogue.
__global__ __launch_bounds__(512, 4) void gemm_exp_kernel(const __bf16* __restrict__ xnb,
                                                          const float* __restrict__ Wg,
                                                          float* __restrict__ sums) {
    __shared__ char lds[49152];
    const int tid  = threadIdx.x;
    const int wid  = tid >> 6;
    const int lane = tid & 63;
    const int l15  = lane & 15;
    const int lhi  = lane >> 4;
    const int wr   = wid >> 1;       // 0..3 : 64-row group
    const int wc   = wid & 1;        // 0..1 : 64-col group

    // bijective XCD swizzle: 3128 = 8 * 391; consecutive logical ids share ct
    // (same W panel) and run on the same XCD -> panel L2-resident.
    const int logical = (blockIdx.x & 7) * (GRIDSZ / 8) + (blockIdx.x >> 3);
    const int rt = logical & 3;
    const int ct = logical >> 2;
    const int r0 = rt * BM;
    const int c0 = ct * BN;

    // ---- B: per-step register staging (thread: cls=tid>>2, qk=tid&3) ----
    const int bcls = tid >> 2;
    const int bqk  = tid & 3;
    const bool bok = (c0 + bcls) < NC;
    float4 bw0, bw1;
    auto loadB = [&](int t) {
        if (bok) {
            const float* src = Wg + (size_t)(c0 + bcls) * ND + t * BK + bqk * 8;
            bw0 = *reinterpret_cast<const float4*>(src);
            bw1 = *reinterpret_cast<const float4*>(src + 4);
        } else {
            bw0 = make_float4(0.f, 0.f, 0.f, 0.f);
            bw1 = bw0;
        }
    };
    auto writeB = [&](int buf) {
        struct alignas(16) bf8s { __bf16 h[8]; };
        bf8s h;
        h.h[0] = (__bf16)bw0.x; h.h[1] = (__bf16)bw0.y; h.h[2] = (__bf16)bw0.z; h.h[3] = (__bf16)bw0.w;
        h.h[4] = (__bf16)bw1.x; h.h[5] = (__bf16)bw1.y; h.h[6] = (__bf16)bw1.z; h.h[7] = (__bf16)bw1.w;
        const int ck = bqk ^ ((bcls >> 1) & 3);
        *reinterpret_cast<bf8s*>(lds + BBASE + buf * BBUF + bcls * 64 + (ck << 4)) = h;
    };

    // ---- A: async global->LDS, linear dest, pre-swizzled source ----
    auto stageA = [&](int t, int buf) {
#pragma unroll
        for (int s = 0; s < 2; ++s) {
            const int lin = s * 8192 + wid * 1024 + (lane << 4);
            const int row = lin >> 6;                 // 64B per row
            const int cnk = (lin >> 4) & 3;
            const int sc  = cnk ^ ((row >> 1) & 3);
            const char* src = (const char*)xnb + (size_t)(r0 + row) * 1024 + t * 64 + sc * 16;
            gload_lds16(src, lds + ABASE + buf * ABUF + s * 8192 + wid * 1024);
        }
    };

    f32x4 acc[4][4] = {};

    auto compute = [&](int buf) {
        bf16x8 a[4], b[4];
#pragma unroll
        for (int i = 0; i < 4; ++i) {
            const int r = wr * 64 + i * 16 + l15;
            const int ck = lhi ^ ((r >> 1) & 3);
            a[i] = *reinterpret_cast<const bf16x8*>(lds + ABASE + buf * ABUF + r * 64 + (ck << 4));
        }
#pragma unroll
        for (int j = 0; j < 4; ++j) {
            const int cls = wc * 64 + j * 16 + l15;
            const int ck  = lhi ^ ((cls >> 1) & 3);
            b[j] = *reinterpret_cast<const bf16x8*>(lds + BBASE + buf * BBUF + cls * 64 + (ck << 4));
        }
#pragma unroll
        for (int i = 0; i < 4; ++i)
#pragma unroll
            for (int j = 0; j < 4; ++j)
                acc[i][j] = __builtin_amdgcn_mfma_f32_16x16x32_bf16(a[i], b[j], acc[i][j], 0, 0, 0);
    };

    // ---- prologue ----
    loadB(0);
    stageA(0, 0);
    writeB(0);
    __syncthreads();          // drains gload_lds (vmcnt) + B ds_writes (lgkm)

#pragma unroll 1
    for (int t = 0; t < NKS; ++t) {
        const int buf = t & 1;
        if (t + 1 < NKS) {
            loadB(t + 1);             // issue early: HBM/L2 latency hides under compute
            stageA(t + 1, buf ^ 1);   // async into alternate A buffer
        }
        compute(buf);
        if (t + 1 < NKS) writeB(buf ^ 1);  // alternate B buffer: no WAR with readers
        __syncthreads();              // ONE barrier: vmcnt+lgkm drained, buffers swap
    }

    // ---- epilogue: exp + row-sum over 64 cols + atomic ----
#pragma unroll
    for (int i = 0; i < 4; ++i) {
#pragma unroll
        for (int r = 0; r < 4; ++r) {
            float v = 0.f;
#pragma unroll
            for (int j = 0; j < 4; ++j) {
                const int c = c0 + wc * 64 + j * 16 + l15;
                v += (c < NC) ? __expf(SSCALE * acc[i][j][r]) : 0.f;
            }
            v += __shfl_xor(v, 1);
            v += __shfl_xor(v, 2);
            v += __shfl_xor(v, 4);
            v += __shfl_xor(v, 8);
            if (l15 == 0) {
                const int row = r0 + wr * 64 + i * 16 + lhi * 4 + r;
                atomicAdd(&sums[row], v);
            }
        }
    }
}

__global__ void finalize_kernel(const float* __restrict__ sums, const float* __restrict__ tgt,
                                float* __restrict__ out) {
    const int tid  = threadIdx.x;
    const int wid  = tid >> 6;
    const int lane = tid & 63;
    float t  = tgt[tid];
    const float se = sums[tid];
    t = fminf(fmaxf(t, -1.0f + 1e-7f), 1.0f - 1e-7f);
    const float numer = SSCALE * cosf(acosf(t) + MMARGIN);
    const float excl  = se - expf(SSCALE * t);
    float L = numer - logf(expf(numer) + excl);
#pragma unroll
    for (int m = 1; m < 64; m <<= 1) L += __shfl_xor(L, m);
    __shared__ float ws2[16];
    if (lane == 0) ws2[wid] = L;
    __syncthreads();
    if (tid == 0) {
        float tot = 0.f;
        for (int i = 0; i < 16; ++i) tot += ws2[i];
        out[0] = -(tot / (float)NB);
    }
}

extern "C" void kernel_launch(void* const* d_in, const int* in_sizes, int n_in,
                              void* d_out, int out_size, void* d_ws, size_t ws_size,
                              hipStream_t stream) {
    const float* x      = (const float*)d_in[0];
    const int*   labels = (const int*)d_in[1];
    const float* W      = (const float*)d_in[2];
    float* out = (float*)d_out;

    char* wsb = (char*)d_ws;
    __bf16* xnb  = (__bf16*)wsb;
    float*  sums = (float*)(wsb + (size_t)NB * ND * 2);
    float*  tgt  = sums + NB;

    hipMemsetAsync(sums, 0, NB * sizeof(float), stream);
    prep_kernel<<<NB, 256, 0, stream>>>(x, xnb);
    target_kernel<<<NB / 4, 256, 0, stream>>>(xnb, W, labels, tgt);
    gemm_exp_kernel<<<GRIDSZ, 512, 0, stream>>>(xnb, W, sums);
    finalize_kernel<<<1, 1024, 0, stream>>>(sums, tgt, out);
}

// Round 5
// 225.460 us; speedup vs baseline: 3.2002x; 1.0559x over previous
//
#include <hip/hip_runtime.h>
#include <hip/hip_bf16.h>
#include <math.h>

#define NB 1024
#define NC 100000
#define ND 512
#define SSCALE 64.0f
#define MMARGIN 0.5f

#define BM 128
#define BN 128
#define BK 64
#define NKS (ND / BK)                // 8 K-steps
#define NRT (NB / BM)                // 8 row tiles
#define NCT ((NC + BN - 1) / BN)     // 782 col tiles
#define GRIDSZ (NRT * NCT)           // 6256 = 8 * 782 exact -> bijective XCD swizzle

#define ABUF  16384                  // A: 2 x 16KB (128 rows x 128B)
#define BBASE 32768                  // B: 2 x 16KB (128 cls x 128B)
#define BBUF  16384

typedef __bf16 bf16x8 __attribute__((ext_vector_type(8)));
typedef float f32x4 __attribute__((ext_vector_type(4)));

__device__ __forceinline__ void gload_lds16(const void* g, void* l) {
    __builtin_amdgcn_global_load_lds(
        (const __attribute__((address_space(1))) unsigned int*)g,
        (__attribute__((address_space(3))) unsigned int*)l, 16, 0, 0);
}

// ---------------------------------------------------------------------------
// ws layout: [0,1MB) xnb bf16[NB][ND] ; then sums float[NB] ; tgt float[NB]
// ---------------------------------------------------------------------------

__global__ void prep_kernel(const float* __restrict__ x, __bf16* __restrict__ xnb) {
    const int row = blockIdx.x;
    const int tid = threadIdx.x;
    const float2 v = *reinterpret_cast<const float2*>(x + (size_t)row * ND + tid * 2);
    float ss = v.x * v.x + v.y * v.y;
#pragma unroll
    for (int m = 1; m < 64; m <<= 1) ss += __shfl_xor(ss, m);
    __shared__ float wsum[4];
    if ((tid & 63) == 0) wsum[tid >> 6] = ss;
    __syncthreads();
    const float tot = wsum[0] + wsum[1] + wsum[2] + wsum[3];
    const float inv = 1.0f / fmaxf(sqrtf(tot), 1e-12f);
    __bf16* dst = xnb + (size_t)row * ND + tid * 2;
    dst[0] = (__bf16)(v.x * inv);
    dst[1] = (__bf16)(v.y * inv);
}

__global__ void target_kernel(const __bf16* __restrict__ xnb, const float* __restrict__ Wg,
                              const int* __restrict__ labels, float* __restrict__ tgt) {
    const int wid  = threadIdx.x >> 6;
    const int lane = threadIdx.x & 63;
    const int row  = blockIdx.x * 4 + wid;
    const int lab  = labels[row];
    const int k    = lane * 8;
    const bf16x8 xv = *reinterpret_cast<const bf16x8*>(xnb + (size_t)row * ND + k);
    const float* wr = Wg + (size_t)lab * ND + k;
    const float4 w0 = *reinterpret_cast<const float4*>(wr);
    const float4 w1 = *reinterpret_cast<const float4*>(wr + 4);
    float s = (float)xv[0] * w0.x + (float)xv[1] * w0.y + (float)xv[2] * w0.z + (float)xv[3] * w0.w
            + (float)xv[4] * w1.x + (float)xv[5] * w1.y + (float)xv[6] * w1.z + (float)xv[7] * w1.w;
#pragma unroll
    for (int m = 1; m < 64; m <<= 1) s += __shfl_xor(s, m);
    if (lane == 0) tgt[row] = s;
}

// 128x128x64 GEMM, both operands LDS-double-buffered, ONE counted-vmcnt barrier
// per K-step (T4: B's 8 reg-loads stay in flight across the barrier; only A's 4
// gload_lds are retired). B register pipeline is depth-2 (bw0/bw1, static idx).
// A (bf16) via global_load_lds w16 with pre-swizzled source; B (fp32 W) cvt'd
// to bf16 on the write path. 64KB LDS -> 2 blocks/CU. Fused exp+rowsum epilogue.
__global__ __launch_bounds__(256, 2) void gemm_exp_kernel(const __bf16* __restrict__ xnb,
                                                          const float* __restrict__ Wg,
                                                          float* __restrict__ sums) {
    __shared__ char lds[65536];
    const int tid  = threadIdx.x;
    const int wid  = tid >> 6;
    const int lane = tid & 63;
    const int l15  = lane & 15;
    const int lhi  = lane >> 4;
    const int wr   = wid >> 1;       // 0..1 : 64-row group
    const int wc   = wid & 1;        // 0..1 : 64-col group

    // bijective XCD swizzle: 6256 = 8*782; consecutive logicals share ct (same
    // W panel) -> panel L2-resident per XCD.
    const int logical = (blockIdx.x & 7) * (GRIDSZ / 8) + (blockIdx.x >> 3);
    const int rt = logical & 7;
    const int ct = logical >> 3;
    const int r0 = rt * BM;
    const int c0 = ct * BN;

    // ---- B: 8 float4 loads per K-step (bcls = l*32 + tid>>3, chunk = tid&7) ----
    const int bcls = tid >> 3;
    const int bqp  = tid & 7;
    auto loadB = [&](int t, float4 (&bw)[8]) {
#pragma unroll
        for (int l = 0; l < 4; ++l) {
            const int cls = l * 32 + bcls;
            const float* src = Wg + (size_t)(c0 + cls) * ND + t * BK + bqp * 8;
            if (c0 + cls < NC) {
                bw[l * 2]     = *reinterpret_cast<const float4*>(src);
                bw[l * 2 + 1] = *reinterpret_cast<const float4*>(src + 4);
            } else {
                bw[l * 2]     = make_float4(0.f, 0.f, 0.f, 0.f);
                bw[l * 2 + 1] = make_float4(0.f, 0.f, 0.f, 0.f);
            }
        }
    };
    auto writeB = [&](float4 (&bw)[8], int buf) {
#pragma unroll
        for (int l = 0; l < 4; ++l) {
            const int cls = l * 32 + bcls;
            struct alignas(16) bf8s { __bf16 h[8]; };
            bf8s h;
            const float4 v0 = bw[l * 2], v1 = bw[l * 2 + 1];
            h.h[0] = (__bf16)v0.x; h.h[1] = (__bf16)v0.y; h.h[2] = (__bf16)v0.z; h.h[3] = (__bf16)v0.w;
            h.h[4] = (__bf16)v1.x; h.h[5] = (__bf16)v1.y; h.h[6] = (__bf16)v1.z; h.h[7] = (__bf16)v1.w;
            const int byte = BBASE + buf * BBUF + cls * 128 + ((bqp ^ (cls & 7)) << 4);
            *reinterpret_cast<bf8s*>(lds + byte) = h;
        }
    };

    // ---- A: 4 async gload_lds, linear dest, pre-swizzled source (rule 21) ----
    auto stageA = [&](int t, int buf) {
#pragma unroll
        for (int it = 0; it < 4; ++it) {
            const int row = it * 32 + wid * 8 + (lane >> 3);
            const int c   = lane & 7;
            const int lc  = c ^ (row & 7);
            const char* src = (const char*)xnb + (size_t)(r0 + row) * (ND * 2) + t * (BK * 2) + lc * 16;
            gload_lds16(src, lds + buf * ABUF + it * 4096 + wid * 1024);
        }
    };

    f32x4 acc[4][4] = {};

    auto compute = [&](int buf) {
#pragma unroll
        for (int kk = 0; kk < 2; ++kk) {
            bf16x8 a[4], b[4];
#pragma unroll
            for (int i = 0; i < 4; ++i) {
                const int r = wr * 64 + i * 16 + l15;
                const int byte = buf * ABUF + r * 128 + ((((kk << 2) | lhi) ^ (r & 7)) << 4);
                a[i] = *reinterpret_cast<const bf16x8*>(lds + byte);
            }
#pragma unroll
            for (int j = 0; j < 4; ++j) {
                const int cc = wc * 64 + j * 16 + l15;
                const int byte = BBASE + buf * BBUF + cc * 128 + ((((kk << 2) | lhi) ^ (cc & 7)) << 4);
                b[j] = *reinterpret_cast<const bf16x8*>(lds + byte);
            }
#pragma unroll
            for (int i = 0; i < 4; ++i)
#pragma unroll
                for (int j = 0; j < 4; ++j)
                    acc[i][j] = __builtin_amdgcn_mfma_f32_16x16x32_bf16(a[i], b[j], acc[i][j], 0, 0, 0);
        }
    };

    float4 bw0[8], bw1[8];

    // ---- prologue: B(0)->bw0, A(0)->buf0, B(1)->bw1, write B(0), barrier ----
    loadB(0, bw0);
    stageA(0, 0);
    loadB(1, bw1);
    writeB(bw0, 0);   // compiler-inserted vmcnt retires B(0); A(0)+B(1) stay in flight
    asm volatile("s_waitcnt vmcnt(8) lgkmcnt(0)\n\ts_barrier" ::: "memory");  // A(0) done, B(1) in flight

    // ---- main loop: manually 2-unrolled for static bw0/bw1 indexing (rule 20) ----
#pragma unroll 1
    for (int tt = 0; tt < NKS; tt += 2) {
        {   // even step t=tt: compute buf0; write B(t+1) from bw1; load B(t+2)->bw0
            const int t = tt;
            if (t + 1 < NKS) stageA(t + 1, 1);     // A first: FIFO lets vmcnt(8) retire exactly A
            if (t + 2 < NKS) loadB(t + 2, bw0);
            compute(0);
            if (t + 1 < NKS) writeB(bw1, 1);
            if (t + 2 < NKS) asm volatile("s_waitcnt vmcnt(8) lgkmcnt(0)\n\ts_barrier" ::: "memory");
            else             asm volatile("s_waitcnt vmcnt(0) lgkmcnt(0)\n\ts_barrier" ::: "memory");
        }
        {   // odd step t=tt+1: compute buf1; write B(t+1) from bw0; load B(t+2)->bw1
            const int t = tt + 1;
            if (t + 1 < NKS) stageA(t + 1, 0);
            if (t + 2 < NKS) loadB(t + 2, bw1);
            compute(1);
            if (t + 1 < NKS) writeB(bw0, 0);
            if (t + 2 < NKS) asm volatile("s_waitcnt vmcnt(8) lgkmcnt(0)\n\ts_barrier" ::: "memory");
            else             asm volatile("s_waitcnt vmcnt(0) lgkmcnt(0)\n\ts_barrier" ::: "memory");
        }
    }

    // ---- epilogue: exp + row-sum over this wave's 64 cols + atomic ----
#pragma unroll
    for (int i = 0; i < 4; ++i) {
#pragma unroll
        for (int r = 0; r < 4; ++r) {
            float v = 0.f;
#pragma unroll
            for (int j = 0; j < 4; ++j) {
                const int c = c0 + wc * 64 + j * 16 + l15;
                v += (c < NC) ? __expf(SSCALE * acc[i][j][r]) : 0.f;
            }
            v += __shfl_xor(v, 1);
            v += __shfl_xor(v, 2);
            v += __shfl_xor(v, 4);
            v += __shfl_xor(v, 8);
            if (l15 == 0) {
                const int row = r0 + wr * 64 + i * 16 + lhi * 4 + r;
                atomicAdd(&sums[row], v);
            }
        }
    }
}

__global__ void finalize_kernel(const float* __restrict__ sums, const float* __restrict__ tgt,
                                float* __restrict__ out) {
    const int tid  = threadIdx.x;
    const int wid  = tid >> 6;
    const int lane = tid & 63;
    float t  = tgt[tid];
    const float se = sums[tid];
    t = fminf(fmaxf(t, -1.0f + 1e-7f), 1.0f - 1e-7f);
    const float numer = SSCALE * cosf(acosf(t) + MMARGIN);
    const float excl  = se - expf(SSCALE * t);
    float L = numer - logf(expf(numer) + excl);
#pragma unroll
    for (int m = 1; m < 64; m <<= 1) L += __shfl_xor(L, m);
    __shared__ float ws2[16];
    if (lane == 0) ws2[wid] = L;
    __syncthreads();
    if (tid == 0) {
        float tot = 0.f;
        for (int i = 0; i < 16; ++i) tot += ws2[i];
        out[0] = -(tot / (float)NB);
    }
}

extern "C" void kernel_launch(void* const* d_in, const int* in_sizes, int n_in,
                              void* d_out, int out_size, void* d_ws, size_t ws_size,
                              hipStream_t stream) {
    const float* x      = (const float*)d_in[0];
    const int*   labels = (const int*)d_in[1];
    const float* W      = (const float*)d_in[2];
    float* out = (float*)d_out;

    char* wsb = (char*)d_ws;
    __bf16* xnb  = (__bf16*)wsb;
    float*  sums = (float*)(wsb + (size_t)NB * ND * 2);
    float*  tgt  = sums + NB;

    hipMemsetAsync(sums, 0, NB * sizeof(float), stream);
    prep_kernel<<<NB, 256, 0, stream>>>(x, xnb);
    target_kernel<<<NB / 4, 256, 0, stream>>>(xnb, W, labels, tgt);
    gemm_exp_kernel<<<GRIDSZ, 256, 0, stream>>>(xnb, W, sums);
    finalize_kernel<<<1, 1024, 0, stream>>>(sums, tgt, out);
}